// Round 4
// baseline (10.474 us; speedup 1.0000x reference)
//
#include <hip/hip_runtime.h>

// ScaledThresholdsQuantization4d: B=8, C=64, H=56, W=56, 255 sorted integer
// thresholds per channel in [-192, 191].
// out = sign>0 ? #{t < floor(x)} : 255 - #{t < floor(x)}, as float32.
//
// R4: occupancy probe. 1024 blocks (half-slice each) -> 4 blocks/CU,
// 16 waves/CU (was 2 blocks/8 waves). Same LUT-by-range-fill structure.
// NT loads for x (read-once), NT stores for out (write-once).

#define C_DIM 64
#define NTH 255
#define LUT_SIZE 385            // q in [-192 .. 192]
#define SLICE 3136              // 56*56
#define HALF_F 1568             // floats per half slice
#define HALF_V4 392             // float4 per half slice = 256 + 136

typedef float vfloat4 __attribute__((ext_vector_type(4)));

__global__ __launch_bounds__(256)
void stq4d_kernel(const float* __restrict__ x,
                  const float* __restrict__ thresholds,
                  const int* __restrict__ signs,
                  float* __restrict__ out)
{
    __shared__ float lut[LUT_SIZE];   // sign-resolved count, as float

    const int bid  = blockIdx.x;      // 0..1023
    const int bc   = bid >> 1;        // b*64 + c
    const int c    = bc & (C_DIM - 1);
    const int half = bid & 1;
    const int tid  = threadIdx.x;

    const size_t base = (size_t)bc * SLICE + (size_t)half * HALF_F;
    const vfloat4* __restrict__ xv = (const vfloat4*)(x + base);
    vfloat4* __restrict__ ov       = (vfloat4*)(out + base);

    // 1) Issue this half-slice's loads first; latency hides under LUT build.
    const vfloat4 v0 = __builtin_nontemporal_load(&xv[tid]);
    vfloat4 v1;
    if (tid < HALF_V4 - 256) v1 = __builtin_nontemporal_load(&xv[tid + 256]);

    // 2) Range-fill LUT. Thread j covers integer q with t[j-1] < q <= t[j]
    //    (t[-1] = -inf, t[255] = +inf): there #{t < q} = j exactly (holds
    //    with duplicate thresholds; empty range when t[j-1] == t[j]).
    //    Thresholds are integer-valued floats, so (int) conversion is exact.
    {
        const int  sign = signs[c];
        const int  j    = tid;                 // 0..255
        const float tjf = (j < NTH) ? thresholds[c * NTH + j] : 193.0f;
        const float tpf = (j > 0)   ? thresholds[c * NTH + j - 1] : -193.0f;
        const int   tj  = (int)tjf;
        const int   tp  = (int)tpf;
        const int   qlo = max(tp + 1, -192);
        const int   qhi = min(tj, 192);
        const float val = (float)(sign > 0 ? j : (NTH - j));
        for (int q = qlo; q <= qhi; ++q) lut[q + 192] = val;
    }
    __syncthreads();

    // 3) Lookup + non-temporal store (output is write-once).
    #define LOOKUP(f) lut[(int)fminf(fmaxf(floorf(f), -192.0f), 192.0f) + 192]
    vfloat4 r0;
    r0.x = LOOKUP(v0.x); r0.y = LOOKUP(v0.y); r0.z = LOOKUP(v0.z); r0.w = LOOKUP(v0.w);
    __builtin_nontemporal_store(r0, &ov[tid]);

    if (tid < HALF_V4 - 256) {
        vfloat4 r1;
        r1.x = LOOKUP(v1.x); r1.y = LOOKUP(v1.y); r1.z = LOOKUP(v1.z); r1.w = LOOKUP(v1.w);
        __builtin_nontemporal_store(r1, &ov[tid + 256]);
    }
    #undef LOOKUP
}

extern "C" void kernel_launch(void* const* d_in, const int* in_sizes, int n_in,
                              void* d_out, int out_size, void* d_ws, size_t ws_size,
                              hipStream_t stream) {
    const float* x          = (const float*)d_in[0];
    const float* thresholds = (const float*)d_in[1];
    const int*   signs      = (const int*)d_in[2];
    float*       out        = (float*)d_out;

    // 1024 blocks, one half-(b,c)-slice of 1568 elements each.
    stq4d_kernel<<<1024, 256, 0, stream>>>(x, thresholds, signs, out);
}